// Round 4
// baseline (576.141 us; speedup 1.0000x reference)
//
#include <hip/hip_runtime.h>
#include <hip/hip_bf16.h>
#include <math.h>

// ---------------------------------------------------------------------------
// GauntTensorProductAllParitiesS2Grid  (N=1024, MUL=C=128, lmax_in=3,
// lmax_out=6, grid 8x16=128, 3 parity configs)
//
//   K0a tables2    : YinH f16 [128g][16k], YowH f16 [64kout][128g] (par. over g,(l,m))
//   K0b prep_wot   : WoTH f16 [ip][l][d][c]   (for stage4 B-frags)
//   K0c prep_win   : WtIn f16 [in][ip][l][c][u] (for stage1 B-frags)
//   K0d transpose_x: xT  f16 [in][ch][k][n][u] (coalesced transpose of x)
//   K1  stage1_mfma: per (ip,in,l,ntile): GEMM n x c (K=u), B reg-cached
//                    -> c1H/c2H f16 [ip][n][c][16]
//   K2  fused23    : per (ip,n): MFMA GEMM1 (xYin), P=G1*G2 via LDS,
//                    MFMA GEMM2 (xYowT) -> zH f16 [ip][k49][n][c]
//   K3  stage4_v2  : per (ip,ntile64,dtile16): all 49 k -> full-line out writes
// ---------------------------------------------------------------------------

#define PI_D 3.14159265358979323846

using short8 = __attribute__((ext_vector_type(8))) short;
using f32x4  = __attribute__((ext_vector_type(4))) float;

__device__ __host__ constexpr int lof_in(int k)  { return k>=9?3 : k>=4?2 : k>=1?1 : 0; }
__device__ __host__ constexpr int lof_out(int k) { return k>=36?6 : k>=25?5 : k>=16?4 : k>=9?3 : k>=4?2 : k>=1?1 : 0; }

__device__ __forceinline__ unsigned short f2h(float f) {
  _Float16 h = (_Float16)f;
  return __builtin_bit_cast(unsigned short, h);
}

// ---------------------------------------------------------------------------
// K0a: tables, parallel over g (blocks) and (l,m) (threads).
// t = l*l + l + m  (== k index)
// ---------------------------------------------------------------------------
__global__ void tables2(unsigned short* __restrict__ YinH,
                        unsigned short* __restrict__ YowH)
{
  const int g = blockIdx.x;       // 0..127
  const int t = threadIdx.x;      // 0..63
  if (t >= 64 || g >= 128) return;

  const int b = g >> 4;
  const int a = g & 15;

  const double xb_[8] = {
    -0.9602898564975362, -0.7966664774136267, -0.5255324099163290, -0.1834346424956498,
     0.1834346424956498,  0.5255324099163290,  0.7966664774136267,  0.9602898564975362};
  const double wb_[8] = {
     0.10122853629037626, 0.22238103445337447, 0.31370664587788729, 0.36268378337836198,
     0.36268378337836198, 0.31370664587788729, 0.22238103445337447, 0.10122853629037626};

  if (t >= 49) {                      // zero-pad rows 49..63 of YowH
    YowH[t * 128 + g] = 0;
    return;
  }

  const int l  = lof_out(t);
  const int m  = t - l * l - l;
  const int am = m < 0 ? -m : m;

  const double x = xb_[b];
  const double s = sqrt(fmax(0.0, 1.0 - x * x));
  const double alpha = (2.0 * PI_D / 16.0) * (double)a;

  // P[am][am], then upward recurrence in l
  double pmm = 1.0;
  for (int j = 1; j <= am; ++j) pmm = -(double)(2 * j - 1) * s * pmm;
  double p = pmm, pm1 = 0.0;
  for (int ll = am; ll < l; ++ll) {
    double pn = ((double)(2 * ll + 1) * x * p - (double)(ll + am) * pm1) / (double)(ll + 1 - am);
    pm1 = p; p = pn;
  }

  double fr = 1.0;
  for (int j = l - am + 1; j <= l + am; ++j) fr /= (double)j;
  const double norm = sqrt((double)(2 * l + 1) / (4.0 * PI_D) * fr);
  double az;
  if (m > 0)       az = sqrt(2.0) * cos((double)m * alpha);
  else if (m == 0) az = 1.0;
  else             az = sqrt(2.0) * sin((double)am * alpha);

  const double Y  = norm * p * az;
  const double qw = wb_[b] * (2.0 * PI_D / 16.0);

  if (t < 16) YinH[g * 16 + t] = f2h((float)Y);
  YowH[t * 128 + g] = f2h((float)(Y * qw));
}

// ---------------------------------------------------------------------------
// K0b: WoTH[ip][l][d][c] = f16(W_out[ip][l][c][d]).  1344 blocks x 256.
// ---------------------------------------------------------------------------
__global__ void prep_wot(const float* __restrict__ Wo, unsigned short* __restrict__ WoTH)
{
  const int e = blockIdx.x * 256 + threadIdx.x;   // < 344064
  const int c = e & 127;
  const int d = (e >> 7) & 127;
  const int r = e >> 14;                          // ip*7 + l
  WoTH[((size_t)r * 128 + d) * 128 + c] = f2h(Wo[((size_t)r * 128 + c) * 128 + d]);
}

// ---------------------------------------------------------------------------
// K0c: WtIn[in][ip][l][c][u] = f16(W{in}[ip][l][u][c]).  1536 blocks x 256.
// ---------------------------------------------------------------------------
__global__ void prep_win(const float* __restrict__ W1, const float* __restrict__ W2,
                         unsigned short* __restrict__ WtIn)
{
  const int e = blockIdx.x * 256 + threadIdx.x;   // < 393216
  const int u = e & 127;
  const int c = (e >> 7) & 127;
  const int r = e >> 14;                          // in*12 + ip*4 + l
  const int in = r / 12;
  const int rr = r - in * 12;                     // ip*4+l
  const float* W = (in == 0) ? W1 : W2;
  WtIn[e] = f2h(W[((size_t)rr * 128 + u) * 128 + c]);
}

// ---------------------------------------------------------------------------
// K0d: xT[in][ch][k][n][u] = f16(x[n][u][ch][k]).  1024 blocks x 256.
// block: (in = bid>>9, n-pair nb = bid&511); thread: (ug = tid>>5, chk = tid&31)
// global loads fully coalesced (chk fastest across lanes).
// ---------------------------------------------------------------------------
__global__ __launch_bounds__(256) void transpose_x(
    const float* __restrict__ x1, const float* __restrict__ x2,
    unsigned short* __restrict__ xT)
{
  const int bid = blockIdx.x;
  const int in = bid >> 9;
  const int nb = bid & 511;
  const int tid = threadIdx.x;
  const int ug  = tid >> 5;     // 0..7  (u-strip of 16)
  const int chk = tid & 31;     // ch*16 + k
  const float* src = ((in == 0) ? x1 : x2) + (size_t)nb * 2 * 4096;
  unsigned short* dst = xT + (size_t)in * 2 * 16 * 1024 * 128;

#pragma unroll
  for (int n = 0; n < 2; ++n) {
    unsigned int w[8];
#pragma unroll
    for (int q = 0; q < 8; ++q) {
      const int u0 = ug * 16 + 2 * q;
      const unsigned short lo = f2h(src[n * 4096 + (u0 + 0) * 32 + chk]);
      const unsigned short hi = f2h(src[n * 4096 + (u0 + 1) * 32 + chk]);
      w[q] = (unsigned)lo | ((unsigned)hi << 16);
    }
    unsigned short* pd = dst + (((size_t)chk * 1024 + nb * 2 + n) * 128 + ug * 16);
    ((uint4*)pd)[0] = make_uint4(w[0], w[1], w[2], w[3]);
    ((uint4*)pd)[1] = make_uint4(w[4], w[5], w[6], w[7]);
  }
}

// ---------------------------------------------------------------------------
// K1: stage1 via MFMA.  bid = ((ip*2+in)*16 + ntile)*4 + l  -> 384 blocks x 256.
// wave wv: n-tile 16 at n0 = ntile*64 + wv*16.  GEMM: D[n][c] = A[n][u] B[u][c].
// B-frags (WtIn[in][ip][l][c][u]) reg-cached across the whole l-group.
// out: c1H/c2H[ip][n][c][16] f16 (scattered 2B stores; lines completed by the
// 4 adjacent l-blocks -> L2 write-combine).
// ---------------------------------------------------------------------------
__global__ __launch_bounds__(256) void stage1_mfma(
    const unsigned short* __restrict__ xT, const unsigned short* __restrict__ WtIn,
    unsigned short* __restrict__ c1H, unsigned short* __restrict__ c2H)
{
  const int bid = blockIdx.x;
  const int l  = bid & 3;
  const int nt = (bid >> 2) & 15;
  const int in = (bid >> 6) & 1;
  const int ip = bid >> 7;
  const int tid  = threadIdx.x;
  const int wv   = tid >> 6;
  const int lane = tid & 63;
  const int lr   = lane & 15;
  const int lg   = lane >> 4;
  const int n0   = nt * 64 + wv * 16;

  const int flip = (in == 0) ? (ip == 2 ? 1 : 0) : (ip == 1 ? 1 : 0);
  const int ch   = (l & 1) ^ flip;

  const unsigned short* A0 = xT + ((size_t)in * 2 + ch) * 16 * 1024 * 128;
  const unsigned short* B0 = WtIn + (((size_t)in * 3 + ip) * 4 + l) * 128 * 128;
  unsigned short* outp = ((in == 0) ? c1H : c2H) + (size_t)ip * 1024 * 128 * 16;

  const int kcnt  = 2 * l + 1;
  const int kbase = l * l;
  const float ism = 0.08838834764831845f;  // 1/sqrt(128)

#pragma unroll
  for (int cp = 0; cp < 2; ++cp) {
    short8 bf[4][4];   // [ct][ks], c-half cp
#pragma unroll
    for (int ct = 0; ct < 4; ++ct)
#pragma unroll
      for (int ks = 0; ks < 4; ++ks)
        bf[ct][ks] = *(const short8*)(B0 + (size_t)(cp * 64 + ct * 16 + lr) * 128 + ks * 32 + lg * 8);

    for (int kk = 0; kk < kcnt; ++kk) {
      const int k = kbase + kk;
      short8 af[4];
#pragma unroll
      for (int ks = 0; ks < 4; ++ks)
        af[ks] = *(const short8*)(A0 + ((size_t)k * 1024 + n0 + lr) * 128 + ks * 32 + lg * 8);

      f32x4 acc[4];
#pragma unroll
      for (int ct = 0; ct < 4; ++ct) acc[ct] = (f32x4){0.f, 0.f, 0.f, 0.f};
#pragma unroll
      for (int ks = 0; ks < 4; ++ks)
#pragma unroll
        for (int ct = 0; ct < 4; ++ct)
          acc[ct] = __builtin_amdgcn_mfma_f32_16x16x32_f16(af[ks], bf[ct][ks], acc[ct], 0, 0, 0);

#pragma unroll
      for (int ct = 0; ct < 4; ++ct) {
        const int c = cp * 64 + ct * 16 + lr;
#pragma unroll
        for (int j = 0; j < 4; ++j) {
          const int n = n0 + lg * 4 + j;
          outp[((size_t)n * 128 + c) * 16 + k] = f2h(acc[ct][j] * ism);
        }
      }
    }
  }
}

// ---------------------------------------------------------------------------
// K2: fused stages 2+3 (MFMA f16).  3072 blocks (ip = bid>>10, n = bid&1023),
// 256 threads = 4 waves; wave w owns c-rows 32w..32w+31.
// ---------------------------------------------------------------------------
__global__ __launch_bounds__(256, 3) void fused23_kernel(
    const unsigned short* __restrict__ c1H, const unsigned short* __restrict__ c2H,
    const unsigned short* __restrict__ YinH, const unsigned short* __restrict__ YowH,
    unsigned short* __restrict__ zH)
{
  __shared__ char Pl[32768];   // P[c=128][g=128] f16, byte = m*256 + (g*2 ^ ((m&7)<<4))
  const int bid = blockIdx.x;
  const int ip  = bid >> 10;
  const int n   = bid & 1023;
  const int tid = threadIdx.x;
  const int w    = tid >> 6;
  const int lane = tid & 63;
  const int lr   = lane & 15;
  const int lg   = lane >> 4;

  const short8 Z8 = {0, 0, 0, 0, 0, 0, 0, 0};

  short8 a1[2], a2[2];
  const size_t cbase = ((size_t)ip * 1024 + n) * 128 * 16;
#pragma unroll
  for (int mti = 0; mti < 2; ++mti) {
    const int c = (2 * w + mti) * 16 + lr;
    a1[mti] = Z8; a2[mti] = Z8;
    if (lg < 2) {
      a1[mti] = *(const short8*)(c1H + cbase + (size_t)c * 16 + lg * 8);
      a2[mti] = *(const short8*)(c2H + cbase + (size_t)c * 16 + lg * 8);
    }
  }

#pragma unroll
  for (int h = 0; h < 2; ++h) {
    short8 yb[4];
#pragma unroll
    for (int gq = 0; gq < 4; ++gq) {
      const int g = (h * 4 + gq) * 16 + lr;
      yb[gq] = Z8;
      if (lg < 2) yb[gq] = *(const short8*)(YinH + (size_t)g * 16 + lg * 8);
    }
    f32x4 G1[2][4], G2[2][4];
#pragma unroll
    for (int mti = 0; mti < 2; ++mti)
#pragma unroll
      for (int gq = 0; gq < 4; ++gq) {
        G1[mti][gq] = (f32x4){0.f, 0.f, 0.f, 0.f};
        G2[mti][gq] = (f32x4){0.f, 0.f, 0.f, 0.f};
        G1[mti][gq] = __builtin_amdgcn_mfma_f32_16x16x32_f16(a1[mti], yb[gq], G1[mti][gq], 0, 0, 0);
        G2[mti][gq] = __builtin_amdgcn_mfma_f32_16x16x32_f16(a2[mti], yb[gq], G2[mti][gq], 0, 0, 0);
      }
#pragma unroll
    for (int mti = 0; mti < 2; ++mti)
#pragma unroll
      for (int gq = 0; gq < 4; ++gq) {
        const int g = (h * 4 + gq) * 16 + lr;
#pragma unroll
        for (int j = 0; j < 4; ++j) {
          const int m = (2 * w + mti) * 16 + lg * 4 + j;
          const float p = G1[mti][gq][j] * G2[mti][gq][j];
          *(unsigned short*)(Pl + m * 256 + ((g * 2) ^ ((m & 7) << 4))) = f2h(p);
        }
      }
  }
  __syncthreads();

  short8 yw[4][4];
#pragma unroll
  for (int kt = 0; kt < 4; ++kt)
#pragma unroll
    for (int ks = 0; ks < 4; ++ks)
      yw[kt][ks] = *(const short8*)(YowH + (size_t)(kt * 16 + lr) * 128 + ks * 32 + lg * 8);

  f32x4 Zc[2][4];
#pragma unroll
  for (int mti = 0; mti < 2; ++mti)
#pragma unroll
    for (int kt = 0; kt < 4; ++kt) Zc[mti][kt] = (f32x4){0.f, 0.f, 0.f, 0.f};

#pragma unroll
  for (int ks = 0; ks < 4; ++ks) {
    short8 ap[2];
#pragma unroll
    for (int mti = 0; mti < 2; ++mti) {
      const int m = (2 * w + mti) * 16 + lr;
      ap[mti] = *(const short8*)(Pl + m * 256 + ((ks * 64 + lg * 16) ^ ((m & 7) << 4)));
    }
#pragma unroll
    for (int mti = 0; mti < 2; ++mti)
#pragma unroll
      for (int kt = 0; kt < 4; ++kt)
        Zc[mti][kt] = __builtin_amdgcn_mfma_f32_16x16x32_f16(ap[mti], yw[kt][ks], Zc[mti][kt], 0, 0, 0);
  }

#pragma unroll
  for (int mti = 0; mti < 2; ++mti)
#pragma unroll
    for (int kt = 0; kt < 4; ++kt) {
      const int kout = kt * 16 + lr;
      if (kout < 49) {
        const int c0 = (2 * w + mti) * 16 + lg * 4;
        uint2 v;
        v.x = (unsigned)f2h(Zc[mti][kt][0]) | ((unsigned)f2h(Zc[mti][kt][1]) << 16);
        v.y = (unsigned)f2h(Zc[mti][kt][2]) | ((unsigned)f2h(Zc[mti][kt][3]) << 16);
        *(uint2*)(zH + (((size_t)ip * 49 + kout) * 1024 + n) * 128 + c0) = v;
      }
    }
}

// ---------------------------------------------------------------------------
// K3: stage4 v2.  bid = (ip*16 + ntile)*8 + dtile -> 384 blocks x 256.
// wave wv: n-tile 16 at n0 = ntile*64 + wv*16;  d = dtile*16 + lr.
// Iterates all 49 k (B-frags reloaded once per l) -> out lines fully covered
// by one block -> no HBM write amplification.
// ---------------------------------------------------------------------------
__global__ __launch_bounds__(256) void stage4_v2(
    const unsigned short* __restrict__ zH, const unsigned short* __restrict__ WoTH,
    float* __restrict__ out)
{
  const int bid = blockIdx.x;
  const int dt = bid & 7;
  const int nt = (bid >> 3) & 15;
  const int ip = bid >> 7;
  const int tid  = threadIdx.x;
  const int wv   = tid >> 6;
  const int lane = tid & 63;
  const int lr   = lane & 15;
  const int lg   = lane >> 4;
  const int n0   = nt * 64 + wv * 16;
  const int d    = dt * 16 + lr;

  const unsigned short* Bb = WoTH + (size_t)ip * 7 * 16384;
  const float isc = 0.08838834764831845f;  // 1/sqrt(128)

  for (int l = 0; l <= 6; ++l) {
    short8 bf[4];
#pragma unroll
    for (int ks = 0; ks < 4; ++ks)
      bf[ks] = *(const short8*)(Bb + (size_t)l * 16384 + (size_t)(dt * 16 + lr) * 128 + ks * 32 + lg * 8);

    const int kcnt = 2 * l + 1;
    for (int kk = 0; kk < kcnt; ++kk) {
      const int k = l * l + kk;
      const unsigned short* Ab = zH + ((size_t)ip * 49 + k) * 1024 * 128;
      short8 af[4];
#pragma unroll
      for (int ks = 0; ks < 4; ++ks)
        af[ks] = *(const short8*)(Ab + (size_t)(n0 + lr) * 128 + ks * 32 + lg * 8);

      f32x4 acc = (f32x4){0.f, 0.f, 0.f, 0.f};
#pragma unroll
      for (int ks = 0; ks < 4; ++ks)
        acc = __builtin_amdgcn_mfma_f32_16x16x32_f16(af[ks], bf[ks], acc, 0, 0, 0);

#pragma unroll
      for (int j = 0; j < 4; ++j) {
        const int n = n0 + lg * 4 + j;
        out[(size_t)n * 18816 + ip * 6272 + d * 49 + k] = acc[j] * isc;
      }
    }
  }
}

// ---------------------------------------------------------------------------
extern "C" void kernel_launch(void* const* d_in, const int* in_sizes, int n_in,
                              void* d_out, int out_size, void* d_ws, size_t ws_size,
                              hipStream_t stream)
{
  const float* x1 = (const float*)d_in[0];   // (1024,128,2,16)
  const float* x2 = (const float*)d_in[1];   // (1024,128,2,16)
  const float* W1 = (const float*)d_in[2];   // (3,4,128,128)
  const float* W2 = (const float*)d_in[3];   // (3,4,128,128)
  const float* Wo = (const float*)d_in[4];   // (3,7,128,128)
  float* out = (float*)d_out;                // (1024, 3*128*49)

  char* ws = (char*)d_ws;
  unsigned short* YinH = (unsigned short*)(ws);                 //    4 KB @ 0
  unsigned short* YowH = (unsigned short*)(ws + 16384);         //   16 KB
  unsigned short* WoTH = (unsigned short*)(ws + 65536);         //  672 KB
  unsigned short* WtIn = (unsigned short*)(ws + 786432);        //  768 KB
  unsigned short* xT   = (unsigned short*)(ws + 2097152);       // 16.8 MB
  unsigned short* c1H  = (unsigned short*)(ws + 18874368);      // 12.6 MB
  unsigned short* c2H  = (unsigned short*)(ws + 31457280);      // 12.6 MB
  unsigned short* zH   = (unsigned short*)(ws + 44040192);      // 38.5 MB (ends ~78.8 MB)

  tables2<<<128, 64, 0, stream>>>(YinH, YowH);
  prep_wot<<<1344, 256, 0, stream>>>(Wo, WoTH);
  prep_win<<<1536, 256, 0, stream>>>(W1, W2, WtIn);
  transpose_x<<<1024, 256, 0, stream>>>(x1, x2, xT);
  stage1_mfma<<<384, 256, 0, stream>>>(xT, WtIn, c1H, c2H);
  fused23_kernel<<<3072, 256, 0, stream>>>(c1H, c2H, YinH, YowH, zH);
  stage4_v2<<<384, 256, 0, stream>>>(zH, WoTH, out);
}